// Round 1
// baseline (163.700 us; speedup 1.0000x reference)
//
#include <hip/hip_runtime.h>
#include <math.h>

#define Bsz 2
#define Dd 160
#define Hh 160
#define Ww 160
#define TH 8
#define TW 32
#define DCHUNK 40
#define NCH 5

__global__ void lncc_zero(float* out) { out[0] = 0.0f; }

__global__ __launch_bounds__(256)
void lncc_main(const float* __restrict__ M,
               const float* __restrict__ R,
               const float* __restrict__ kern,
               float* __restrict__ out)
{
    // LDS: halo tiles for M,R (12 x 37, padded) and 5-channel W-sums (5 x 12 x 33)
    __shared__ float lm[TH + 4][TW + 5];
    __shared__ float lr[TH + 4][TW + 5];
    __shared__ float sw[NCH][TH + 4][TW + 1];
    __shared__ float red[4];

    const int tid = threadIdx.x;
    const int tx  = tid & 31;
    const int ty  = tid >> 5;   // 0..7

    const int w0 = blockIdx.x * TW;
    const int h0 = blockIdx.y * TH;
    const int b  = blockIdx.z >> 2;          // batch
    const int d0 = (blockIdx.z & 3) * DCHUNK;

    const float k0 = kern[0];   // 1/125 (match reference scaling exactly)

    // D-direction ring buffer of plane sums: 5 depths x 5 channels, fully
    // static-indexed after unroll (avoids scratch spill — rule #20).
    float ring[5][NCH];
#pragma unroll
    for (int t = 0; t < 5; ++t)
#pragma unroll
        for (int c = 0; c < NCH; ++c) ring[t][c] = 0.0f;

    float acc = 0.0f;

    for (int s = 0; s < DCHUNK + 4; ++s) {
        const int  dd  = d0 - 2 + s;
        const bool dok = (dd >= 0) && (dd < Dd);
        const size_t slice = (size_t)(b * Dd + (dok ? dd : 0)) * Hh * Ww;
        const float* Mp = M + slice;
        const float* Rp = R + slice;

        // ---- Stage A: load halo tile (zero-padded) ----
        for (int i = tid; i < (TH + 4) * (TW + 4); i += 256) {
            int yy = i / (TW + 4);
            int xx = i - yy * (TW + 4);
            int gh = h0 + yy - 2;
            int gw = w0 + xx - 2;
            float vm = 0.0f, vr = 0.0f;
            if (dok && gh >= 0 && gh < Hh && gw >= 0 && gw < Ww) {
                size_t o = (size_t)gh * Ww + gw;
                vm = Mp[o];
                vr = Rp[o];
            }
            lm[yy][xx] = vm;
            lr[yy][xx] = vr;
        }
        __syncthreads();

        // ---- Stage B: W-direction 5-tap sums of the 5 channels ----
        for (int i = tid; i < (TH + 4) * TW; i += 256) {
            int yy = i >> 5;    // row 0..11
            int x  = i & 31;
            float sm = 0.f, sr = 0.f, smm = 0.f, srr = 0.f, smr = 0.f;
#pragma unroll
            for (int t = 0; t < 5; ++t) {
                float a  = lm[yy][x + t];
                float bb = lr[yy][x + t];
                sm += a;
                sr += bb;
                smm = fmaf(a, a, smm);
                srr = fmaf(bb, bb, srr);
                smr = fmaf(a, bb, smr);
            }
            sw[0][yy][x] = sm;
            sw[1][yy][x] = sr;
            sw[2][yy][x] = smm;
            sw[3][yy][x] = srr;
            sw[4][yy][x] = smr;
        }
        __syncthreads();

        // ---- Stage C: H-direction 5-tap sums -> plane sums, push ring ----
        float pl[NCH];
#pragma unroll
        for (int c = 0; c < NCH; ++c) {
            float v = 0.0f;
#pragma unroll
            for (int j = 0; j < 5; ++j) v += sw[c][ty + j][tx];
            pl[c] = v;
        }

        // shift ring (static indices after unroll)
#pragma unroll
        for (int t = 0; t < 4; ++t)
#pragma unroll
            for (int c = 0; c < NCH; ++c) ring[t][c] = ring[t + 1][c];
#pragma unroll
        for (int c = 0; c < NCH; ++c) ring[4][c] = pl[c];

        // ---- emit corr for output depth d = dd-2 once window full ----
        if (s >= 4) {
            float S[NCH];
#pragma unroll
            for (int c = 0; c < NCH; ++c)
                S[c] = ring[0][c] + ring[1][c] + ring[2][c] + ring[3][c] + ring[4][c];
            float Mm  = S[0] * k0;
            float Rm  = S[1] * k0;
            float MMm = S[2] * k0;
            float RRm = S[3] * k0;
            float MRm = S[4] * k0;
            float Mv = sqrtf(MMm - Mm * Mm + 1e-5f);
            float Rv = sqrtf(RRm - Rm * Rm + 1e-5f);
            acc += (MRm - Mm * Rm) / (Mv * Rv + 1e-5f);
        }
    }

    // ---- block reduction -> single atomic ----
#pragma unroll
    for (int off = 32; off > 0; off >>= 1)
        acc += __shfl_down(acc, off, 64);
    if ((tid & 63) == 0) red[tid >> 6] = acc;
    __syncthreads();
    if (tid == 0) {
        float t = red[0] + red[1] + red[2] + red[3];
        atomicAdd(out, -t * (1.0f / 8192000.0f));  // mean over 2*160^3, negated
    }
}

extern "C" void kernel_launch(void* const* d_in, const int* in_sizes, int n_in,
                              void* d_out, int out_size, void* d_ws, size_t ws_size,
                              hipStream_t stream) {
    const float* M = (const float*)d_in[0];
    const float* R = (const float*)d_in[1];
    const float* K = (const float*)d_in[2];
    float* out = (float*)d_out;

    lncc_zero<<<1, 1, 0, stream>>>(out);

    dim3 grid(Ww / TW, Hh / TH, Bsz * (Dd / DCHUNK));  // (5, 20, 8) = 800 blocks
    lncc_main<<<grid, 256, 0, stream>>>(M, R, K, out);
}

// Round 2
// 143.249 us; speedup vs baseline: 1.1428x; 1.1428x over previous
//
#include <hip/hip_runtime.h>
#include <math.h>

#define Bsz 2
#define Dd 160
#define Hh 160
#define Ww 160
#define TH 16
#define TW 32
#define DCHUNK 20
#define NCH 5
#define NT 512
#define HALO_H (TH + 4)          // 20
#define HALO_W (TW + 4)          // 36
#define APIX (HALO_H * HALO_W)   // 720
#define BPIX (HALO_H * TW)       // 640
#define NSLICE (DCHUNK + 5)      // 25 (24 real + 1 pad for unroll-5)

__global__ void lncc_zero(float* out) { out[0] = 0.0f; }

__global__ __launch_bounds__(NT)
void lncc_main(const float* __restrict__ M,
               const float* __restrict__ R,
               const float* __restrict__ kern,
               float* __restrict__ out)
{
    __shared__ float lm[HALO_H][HALO_W + 1];      // 20 x 37
    __shared__ float lr[HALO_H][HALO_W + 1];
    __shared__ float sw[NCH][HALO_H][TW + 1];     // 5 x 20 x 33
    __shared__ float red[NT / 64];

    const int tid = threadIdx.x;
    const int tx  = tid & 31;
    const int ty  = tid >> 5;                     // 0..15

    const int w0 = blockIdx.x * TW;
    const int h0 = blockIdx.y * TH;
    const int b  = blockIdx.z >> 3;               // batch
    const int d0 = (blockIdx.z & 7) * DCHUNK;

    const float k0 = kern[0];                     // 1/125

    // ---- Stage-A pixel assignment (2 halo pixels / thread, 2nd may be off) ----
    int  g_off[2], l_off[2];
    bool g_ok[2], l_act[2];
#pragma unroll
    for (int p = 0; p < 2; ++p) {
        int i = tid + p * NT;
        bool act = (i < APIX);
        int yy = act ? (i / HALO_W) : 0;
        int xx = act ? (i - yy * HALO_W) : 0;
        int gh = h0 + yy - 2;
        int gw = w0 + xx - 2;
        l_act[p] = act;
        g_ok[p]  = act && gh >= 0 && gh < Hh && gw >= 0 && gw < Ww;
        g_off[p] = gh * Ww + gw;
        l_off[p] = yy * (HALO_W + 1) + xx;
    }
    float* lmf = &lm[0][0];
    float* lrf = &lr[0][0];

    const size_t batch_base = (size_t)b * Dd * Hh * Ww;

    float pm[2], pr[2];
    auto issue = [&](int s) {
        int  dd  = d0 - 2 + s;
        bool dok = (dd >= 0) && (dd < Dd);
        const float* Mp = M + batch_base + (size_t)(dok ? dd : 0) * (Hh * Ww);
        const float* Rp = R + batch_base + (size_t)(dok ? dd : 0) * (Hh * Ww);
#pragma unroll
        for (int p = 0; p < 2; ++p) {
            bool ok = dok && g_ok[p];
            pm[p] = ok ? Mp[g_off[p]] : 0.0f;
            pr[p] = ok ? Rp[g_off[p]] : 0.0f;
        }
    };

    // mod-5 ring slots, statically indexed via inner unroll (no shifting)
    float ring[5][NCH];
#pragma unroll
    for (int t = 0; t < 5; ++t)
#pragma unroll
        for (int c = 0; c < NCH; ++c) ring[t][c] = 0.0f;

    float acc = 0.0f;

    issue(0);

    for (int s5 = 0; s5 < NSLICE; s5 += 5) {
#pragma unroll
        for (int so = 0; so < 5; ++so) {
            const int s = s5 + so;

            // ---- commit prefetched slice to LDS ----
#pragma unroll
            for (int p = 0; p < 2; ++p) {
                if (l_act[p]) {
                    lmf[l_off[p]] = pm[p];
                    lrf[l_off[p]] = pr[p];
                }
            }
            __syncthreads();

            // ---- prefetch next slice (hides under B+C) ----
            if (s + 1 < NSLICE) issue(s + 1);

            // ---- Stage B: W-direction 5-tap sums, 5 channels ----
#pragma unroll
            for (int p = 0; p < 2; ++p) {
                int i = tid + p * NT;
                if (i < BPIX) {
                    int yy = i >> 5;
                    int x  = i & 31;
                    float sm = 0.f, sr = 0.f, smm = 0.f, srr = 0.f, smr = 0.f;
#pragma unroll
                    for (int t = 0; t < 5; ++t) {
                        float a  = lm[yy][x + t];
                        float bb = lr[yy][x + t];
                        sm += a;
                        sr += bb;
                        smm = fmaf(a, a, smm);
                        srr = fmaf(bb, bb, srr);
                        smr = fmaf(a, bb, smr);
                    }
                    sw[0][yy][x] = sm;
                    sw[1][yy][x] = sr;
                    sw[2][yy][x] = smm;
                    sw[3][yy][x] = srr;
                    sw[4][yy][x] = smr;
                }
            }
            __syncthreads();

            // ---- Stage C: H-direction 5-tap -> plane sum into slot `so` ----
#pragma unroll
            for (int c = 0; c < NCH; ++c) {
                ring[so][c] = sw[c][ty][tx] + sw[c][ty + 1][tx] + sw[c][ty + 2][tx]
                            + sw[c][ty + 3][tx] + sw[c][ty + 4][tx];
            }

            // ---- emit corr for depth d0 + (s-4) ----
            if (s >= 4 && s < DCHUNK + 4) {
                float S[NCH];
#pragma unroll
                for (int c = 0; c < NCH; ++c)
                    S[c] = ring[0][c] + ring[1][c] + ring[2][c] + ring[3][c] + ring[4][c];
                float Mm  = S[0] * k0;
                float Rm  = S[1] * k0;
                float MMm = S[2] * k0;
                float RRm = S[3] * k0;
                float MRm = S[4] * k0;
                float Mv = sqrtf(MMm - Mm * Mm + 1e-5f);
                float Rv = sqrtf(RRm - Rm * Rm + 1e-5f);
                acc += (MRm - Mm * Rm) / (Mv * Rv + 1e-5f);
            }
        }
    }

    // ---- block reduction -> one atomic ----
#pragma unroll
    for (int off = 32; off > 0; off >>= 1)
        acc += __shfl_down(acc, off, 64);
    if ((tid & 63) == 0) red[tid >> 6] = acc;
    __syncthreads();
    if (tid == 0) {
        float t = 0.f;
#pragma unroll
        for (int i = 0; i < NT / 64; ++i) t += red[i];
        atomicAdd(out, -t * (1.0f / 8192000.0f));   // mean over 2*160^3, negated
    }
}

extern "C" void kernel_launch(void* const* d_in, const int* in_sizes, int n_in,
                              void* d_out, int out_size, void* d_ws, size_t ws_size,
                              hipStream_t stream) {
    const float* M = (const float*)d_in[0];
    const float* R = (const float*)d_in[1];
    const float* K = (const float*)d_in[2];
    float* out = (float*)d_out;

    lncc_zero<<<1, 1, 0, stream>>>(out);

    dim3 grid(Ww / TW, Hh / TH, Bsz * (Dd / DCHUNK));   // (5, 10, 16) = 800 blocks
    lncc_main<<<grid, NT, 0, stream>>>(M, R, K, out);
}

// Round 4
// 141.989 us; speedup vs baseline: 1.1529x; 1.0089x over previous
//
#include <hip/hip_runtime.h>
#include <math.h>

#define Bsz 2
#define Dd 160
#define Hh 160
#define Ww 160
#define TH 8
#define TW 32
#define DCHUNK 16
#define NCH 5
#define NT 256
#define HALO_H (TH + 4)          // 12
#define HALO_W (TW + 4)          // 36
#define APIX (HALO_H * HALO_W)   // 432
#define BPIX (HALO_H * TW)       // 384
#define NSLICE (DCHUNK + 4)      // 20 slices loaded per chunk
#define SLICE_STRIDE (Hh * Ww)

__global__ void lncc_zero(float* out) { out[0] = 0.0f; }

__global__ __launch_bounds__(NT)
void lncc_main(const float* __restrict__ M,
               const float* __restrict__ R,
               const float* __restrict__ kern,
               float* __restrict__ out)
{
    __shared__ float lm[HALO_H][HALO_W + 1];      // 12 x 37
    __shared__ float lr[HALO_H][HALO_W + 1];
    __shared__ float sw[NCH][HALO_H][TW + 1];     // 5 x 12 x 33
    __shared__ float red[NT / 64];

    const int tid = threadIdx.x;
    const int tx  = tid & 31;
    const int ty  = tid >> 5;                     // 0..7

    const int w0 = blockIdx.x * TW;
    const int h0 = blockIdx.y * TH;
    const int b  = blockIdx.z / 10;               // batch (Dd/DCHUNK = 10)
    const int d0 = (blockIdx.z - b * 10) * DCHUNK;

    const float k0 = kern[0];                     // 1/125

    // ---- Stage-A pixel assignment: 2 halo pixels/thread (2nd partial) ----
    int  g_off[2], l_off[2];
    bool g_ok[2], l_act[2];
#pragma unroll
    for (int p = 0; p < 2; ++p) {
        int i = tid + p * NT;
        bool act = (i < APIX);
        int yy = act ? (i / HALO_W) : 0;
        int xx = act ? (i - yy * HALO_W) : 0;
        int gh = h0 + yy - 2;
        int gw = w0 + xx - 2;
        l_act[p] = act;
        g_ok[p]  = act && gh >= 0 && gh < Hh && gw >= 0 && gw < Ww;
        g_off[p] = gh * Ww + gw;
        l_off[p] = yy * (HALO_W + 1) + xx;
    }
    float* lmf = &lm[0][0];
    float* lrf = &lr[0][0];

    const size_t batch_base = (size_t)b * Dd * SLICE_STRIDE;

    // depth-2 prefetch buffers (parity statically resolved by 10-unroll)
    float pm[2][2], pr[2][2];
    auto issue = [&](int s, int buf) {
        int  dd  = d0 - 2 + s;                    // wave-uniform -> SALU
        bool dok = (dd >= 0) && (dd < Dd);
        const float* Mp = M + batch_base + (size_t)(dok ? dd : 0) * SLICE_STRIDE;
        const float* Rp = R + batch_base + (size_t)(dok ? dd : 0) * SLICE_STRIDE;
#pragma unroll
        for (int p = 0; p < 2; ++p) {
            bool ok = dok && g_ok[p];
            pm[buf][p] = ok ? Mp[g_off[p]] : 0.0f;
            pr[buf][p] = ok ? Rp[g_off[p]] : 0.0f;
        }
    };

    // mod-5 ring of plane sums (statically indexed via unroll)
    float ring[5][NCH];
#pragma unroll
    for (int t = 0; t < 5; ++t)
#pragma unroll
        for (int c = 0; c < NCH; ++c) ring[t][c] = 0.0f;

    float acc = 0.0f;

    issue(0, 0);
    issue(1, 1);

    for (int s10 = 0; s10 < NSLICE; s10 += 10) {
#pragma unroll
        for (int so = 0; so < 10; ++so) {
            const int s    = s10 + so;
            const int buf  = so & 1;      // compile-time after unroll
            const int slot = so % 5;      // compile-time after unroll

            // ---- commit prefetched slice s to LDS ----
#pragma unroll
            for (int p = 0; p < 2; ++p) {
                if (l_act[p]) {
                    lmf[l_off[p]] = pm[buf][p];
                    lrf[l_off[p]] = pr[buf][p];
                }
            }
            __syncthreads();

            // ---- issue load for slice s+2 into freed buffer ----
            if (s + 2 < NSLICE) issue(s + 2, buf);

            // ---- Stage B: W-direction 5-tap sums, 5 channels ----
#pragma unroll
            for (int p = 0; p < 2; ++p) {
                int i = tid + p * NT;
                if (i < BPIX) {                     // p=0 always true
                    int yy = i >> 5;
                    int x  = i & 31;
                    float sm = 0.f, sr = 0.f, smm = 0.f, srr = 0.f, smr = 0.f;
#pragma unroll
                    for (int t = 0; t < 5; ++t) {
                        float a  = lm[yy][x + t];
                        float bb = lr[yy][x + t];
                        sm += a;
                        sr += bb;
                        smm = fmaf(a, a, smm);
                        srr = fmaf(bb, bb, srr);
                        smr = fmaf(a, bb, smr);
                    }
                    sw[0][yy][x] = sm;
                    sw[1][yy][x] = sr;
                    sw[2][yy][x] = smm;
                    sw[3][yy][x] = srr;
                    sw[4][yy][x] = smr;
                }
            }
            __syncthreads();

            // ---- Stage C: H-direction 5-tap -> plane sum into ring[slot] ----
#pragma unroll
            for (int c = 0; c < NCH; ++c) {
                ring[slot][c] = sw[c][ty][tx] + sw[c][ty + 1][tx] + sw[c][ty + 2][tx]
                              + sw[c][ty + 3][tx] + sw[c][ty + 4][tx];
            }

            // ---- emit corr for output depth d0 + (s-4) ----
            if (s >= 4) {
                float S[NCH];
#pragma unroll
                for (int c = 0; c < NCH; ++c)
                    S[c] = ring[0][c] + ring[1][c] + ring[2][c] + ring[3][c] + ring[4][c];
                float Mm  = S[0] * k0;
                float Rm  = S[1] * k0;
                float MMm = S[2] * k0;
                float RRm = S[3] * k0;
                float MRm = S[4] * k0;
                float Mv = sqrtf(MMm - Mm * Mm + 1e-5f);
                float Rv = sqrtf(RRm - Rm * Rm + 1e-5f);
                acc += (MRm - Mm * Rm) / (Mv * Rv + 1e-5f);
            }
        }
    }

    // ---- block reduction -> one atomic ----
#pragma unroll
    for (int off = 32; off > 0; off >>= 1)
        acc += __shfl_down(acc, off, 64);
    if ((tid & 63) == 0) red[tid >> 6] = acc;
    __syncthreads();
    if (tid == 0) {
        float t = 0.f;
#pragma unroll
        for (int i = 0; i < NT / 64; ++i) t += red[i];
        atomicAdd(out, -t * (1.0f / 8192000.0f));   // mean over 2*160^3, negated
    }
}

extern "C" void kernel_launch(void* const* d_in, const int* in_sizes, int n_in,
                              void* d_out, int out_size, void* d_ws, size_t ws_size,
                              hipStream_t stream) {
    const float* M = (const float*)d_in[0];
    const float* R = (const float*)d_in[1];
    const float* K = (const float*)d_in[2];
    float* out = (float*)d_out;

    lncc_zero<<<1, 1, 0, stream>>>(out);

    dim3 grid(Ww / TW, Hh / TH, Bsz * (Dd / DCHUNK));   // (5, 20, 20) = 2000 blocks
    lncc_main<<<grid, NT, 0, stream>>>(M, R, K, out);
}

// Round 5
// 136.166 us; speedup vs baseline: 1.2022x; 1.0428x over previous
//
#include <hip/hip_runtime.h>
#include <math.h>

#define Bsz 2
#define Dd 160
#define Hh 160
#define Ww 160
#define TW 32
#define TH 32
#define DCHUNK 16
#define NT 320
#define NCH 5
#define PDIM 48
#define HROWS (TH + 4)        // 36
#define NSLICE (DCHUNK + 4)   // 20
#define SLICE (Hh * Ww)

__global__ void lncc_zero(float* out) { out[0] = 0.0f; }

// barrier that drains LDS counters only — prefetch global loads stay in flight
__device__ __forceinline__ void bar_lgkm() {
    asm volatile("s_waitcnt lgkmcnt(0)" ::: "memory");
    __builtin_amdgcn_s_barrier();
    asm volatile("" ::: "memory");
}

__global__ __launch_bounds__(NT)
void lncc_main(const float* __restrict__ M,
               const float* __restrict__ R,
               const float* __restrict__ kern,
               float* __restrict__ out)
{
    // W-sums, h-contiguous: sw[ch][w][p], p = halo-row + 4*((w/4)&3) swizzle.
    __shared__ float sw[NCH][TW][PDIM];     // 30 KB
    __shared__ float red[NT / 64];

    const int tid = threadIdx.x;
    const int w0 = blockIdx.x * TW;
    const int h0 = blockIdx.y * TH;
    const int b  = blockIdx.z / (Dd / DCHUNK);
    const int d0 = (blockIdx.z % (Dd / DCHUNK)) * DCHUNK;

    const float k0 = kern[0];               // 1/125

    // ---------------- B-role: W-sums from global (no raw LDS) ----------------
    const bool isB = tid < HROWS * 8;       // 288 units: g = w-quad-group, row = halo row
    const int  g   = tid & 7;
    const int  row = tid >> 3;              // 0..39 (valid < 36)
    const int  gh  = h0 + row - 2;
    const bool hok = isB && gh >= 0 && gh < Hh;
    bool qok[3]; int qoff[3];
#pragma unroll
    for (int k = 0; k < 3; ++k) {
        int gw = w0 - 4 + 4 * (g + k);      // quads are fully in or fully out
        qok[k]  = hok && gw >= 0 && gw <= (Ww - 4);
        qoff[k] = gh * Ww + gw;
    }
    const size_t bbase = (size_t)b * Dd * SLICE;
    const float* Mb = M + bbase;
    const float* Rb = R + bbase;

    float4 cm[3], cr[3];
    auto issue = [&](int s) {
        int dd = d0 - 2 + s;
        bool dok = dd >= 0 && dd < Dd;
        const float* Ms = Mb + (size_t)(dok ? dd : 0) * SLICE;
        const float* Rs = Rb + (size_t)(dok ? dd : 0) * SLICE;
#pragma unroll
        for (int k = 0; k < 3; ++k) {
            bool ok = dok && qok[k];
            cm[k] = ok ? *(const float4*)(Ms + qoff[k]) : make_float4(0.f, 0.f, 0.f, 0.f);
            cr[k] = ok ? *(const float4*)(Rs + qoff[k]) : make_float4(0.f, 0.f, 0.f, 0.f);
        }
    };
    // write base: &sw[0][x0][row + off(g)]; (c,j) folded into imm offsets
    float* swp = &sw[0][g * 4][row + 4 * (g & 3)];

    // ---------------- C-role: H-sums via b128, ring over D ----------------
    const bool isC = tid < 256;
    const int  cw  = tid & 31;
    const int  hg  = (tid >> 5) & 7;        // 4-h column group
    const int  p0  = hg * 4 + 4 * ((cw >> 2) & 3);
    const float* crd = &sw[0][cw][p0];

    float ring[5][NCH][4];
#pragma unroll
    for (int t = 0; t < 5; ++t)
#pragma unroll
        for (int c = 0; c < NCH; ++c)
#pragma unroll
            for (int j = 0; j < 4; ++j) ring[t][c][j] = 0.f;

    float acc = 0.f;
    issue(0);

    for (int s5 = 0; s5 < NSLICE; s5 += 5) {
#pragma unroll
        for (int so = 0; so < 5; ++so) {
            const int s = s5 + so;          // slot = so (static), s%5 == so

            bar_lgkm();                     // sw free: previous C done reading

            if (isB) {
                float am[12], ar[12];
                *(float4*)&am[0] = cm[0]; *(float4*)&am[4] = cm[1]; *(float4*)&am[8] = cm[2];
                *(float4*)&ar[0] = cr[0]; *(float4*)&ar[4] = cr[1]; *(float4*)&ar[8] = cr[2];
                float mm[8], rr[8], mr[8];
#pragma unroll
                for (int k = 0; k < 8; ++k) {
                    float a = am[k + 2], r_ = ar[k + 2];
                    mm[k] = a * a; rr[k] = r_ * r_; mr[k] = a * r_;
                }
                // sliding 5-tap W-sums, outputs j=0..3 (window am[j+2..j+6], mm[j..j+4])
                float sm  = am[2] + am[3] + am[4] + am[5] + am[6];
                float sr_ = ar[2] + ar[3] + ar[4] + ar[5] + ar[6];
                float smm = mm[0] + mm[1] + mm[2] + mm[3] + mm[4];
                float srr = rr[0] + rr[1] + rr[2] + rr[3] + rr[4];
                float smr = mr[0] + mr[1] + mr[2] + mr[3] + mr[4];
#pragma unroll
                for (int j = 0; j < 4; ++j) {
                    if (j) {
                        sm  += am[j + 6] - am[j + 1];
                        sr_ += ar[j + 6] - ar[j + 1];
                        smm += mm[j + 4] - mm[j - 1];
                        srr += rr[j + 4] - rr[j - 1];
                        smr += mr[j + 4] - mr[j - 1];
                    }
                    float* wp = swp + j * PDIM;
                    wp[0 * TW * PDIM] = sm;
                    wp[1 * TW * PDIM] = sr_;
                    wp[2 * TW * PDIM] = smm;
                    wp[3 * TW * PDIM] = srr;
                    wp[4 * TW * PDIM] = smr;
                }
                if (s + 1 < NSLICE) issue(s + 1);   // regs free now; flies across barriers
            }

            bar_lgkm();                     // sw published

            if (isC) {
                float hs[NCH][4];
#pragma unroll
                for (int c = 0; c < NCH; ++c) {
                    float4 A  = *(const float4*)(crd + c * TW * PDIM);
                    float4 Bq = *(const float4*)(crd + c * TW * PDIM + 4);
                    float v0 = A.x, v1 = A.y, v2 = A.z, v3 = A.w;
                    float v4 = Bq.x, v5 = Bq.y, v6 = Bq.z, v7 = Bq.w;
                    hs[c][0] = v0 + v1 + v2 + v3 + v4;
                    hs[c][1] = hs[c][0] + v5 - v0;
                    hs[c][2] = hs[c][1] + v6 - v1;
                    hs[c][3] = hs[c][2] + v7 - v2;
#pragma unroll
                    for (int j = 0; j < 4; ++j) ring[so][c][j] = hs[c][j];
                }
                if (s >= 4) {
#pragma unroll
                    for (int j = 0; j < 4; ++j) {
                        float S[NCH];
#pragma unroll
                        for (int c = 0; c < NCH; ++c)
                            S[c] = ring[0][c][j] + ring[1][c][j] + ring[2][c][j]
                                 + ring[3][c][j] + ring[4][c][j];
                        float Mm  = S[0] * k0;
                        float Rm  = S[1] * k0;
                        float MMm = S[2] * k0;
                        float RRm = S[3] * k0;
                        float MRm = S[4] * k0;
                        float Mv = sqrtf(MMm - Mm * Mm + 1e-5f);
                        float Rv = sqrtf(RRm - Rm * Rm + 1e-5f);
                        acc += (MRm - Mm * Rm) / (Mv * Rv + 1e-5f);
                    }
                }
            }
        }
    }

    // ---------------- reduction ----------------
#pragma unroll
    for (int off = 32; off; off >>= 1) acc += __shfl_down(acc, off, 64);
    if ((tid & 63) == 0) red[tid >> 6] = acc;
    __syncthreads();
    if (tid == 0) {
        float t = red[0] + red[1] + red[2] + red[3] + red[4];
        atomicAdd(out, -t * (1.0f / 8192000.0f));   // mean over 2*160^3, negated
    }
}

extern "C" void kernel_launch(void* const* d_in, const int* in_sizes, int n_in,
                              void* d_out, int out_size, void* d_ws, size_t ws_size,
                              hipStream_t stream) {
    const float* M = (const float*)d_in[0];
    const float* R = (const float*)d_in[1];
    const float* K = (const float*)d_in[2];
    float* out = (float*)d_out;

    lncc_zero<<<1, 1, 0, stream>>>(out);

    dim3 grid(Ww / TW, Hh / TH, Bsz * (Dd / DCHUNK));   // (5, 5, 20) = 500 blocks
    lncc_main<<<grid, NT, 0, stream>>>(M, R, K, out);
}